// Round 1
// baseline (441.632 us; speedup 1.0000x reference)
//
#include <hip/hip_runtime.h>

#define NPTS 8192
#define NBATCH 4
#define NN 16
#define RAD2 0.25f
#define EPSF 1e-4f
#define TILE 2048
#define PPB 64
#define NTHREADS 256
#define NBLOCKS (NBATCH * NPTS / PPB)   // 512

__global__ __launch_bounds__(NTHREADS)
void knn_loss_kernel(const float* __restrict__ pts, float* __restrict__ block_sums) {
  __shared__ float4 tile[TILE];           // 32 KiB
  __shared__ float cand[4 * 64 * 17];     // 17 KiB, stride-17 to dodge bank alias

  const int tid = threadIdx.x;
  const int wave = tid >> 6;
  const int lane = tid & 63;
  const int bid = blockIdx.x;
  const int b = bid / (NPTS / PPB);
  const int base = (bid % (NPTS / PPB)) * PPB;
  const float* __restrict__ bp = pts + (size_t)b * NPTS * 3;

  // each wave's lane l owns point base+l; waves scan disjoint j-quarters
  const int i = base + lane;
  const float xi = bp[i * 3 + 0];
  const float yi = bp[i * 3 + 1];
  const float zi = bp[i * 3 + 2];

  float td[NN];
#pragma unroll
  for (int k = 0; k < NN; ++k) td[k] = 1e30f;
  float thrmax = 1e30f;   // max of td[]
  float lim = RAD2;       // min(thrmax, RAD2): only in-radius pts can matter

  for (int tb = 0; tb < NPTS; tb += TILE) {
    // cooperative stage: global -> LDS float4 (w unused)
    for (int p = tid; p < TILE; p += NTHREADS) {
      const float* s = bp + (size_t)(tb + p) * 3;
      tile[p] = make_float4(s[0], s[1], s[2], 0.0f);
    }
    __syncthreads();
    const int jb = wave * (TILE / 4);
    for (int jj = 0; jj < TILE / 4; ++jj) {
      const float4 q = tile[jb + jj];     // wave-uniform addr -> broadcast
      const float dx = q.x - xi;
      const float dy = q.y - yi;
      const float dz = q.z - zi;
      const float d2 = fmaf(dx, dx, fmaf(dy, dy, dz * dz));
      // d2 == 0 exactly <=> self (min pair d2 ~5e-5 >> fp error)
      if (d2 < lim && d2 != 0.0f) {
        // replace current max slot (fully unrolled -> stays in VGPRs)
        bool done = false;
#pragma unroll
        for (int k = 0; k < NN; ++k) {
          const bool hit = (!done) && (td[k] == thrmax);
          if (hit) td[k] = d2;
          done = done || hit;
        }
        thrmax = td[0];
#pragma unroll
        for (int k = 1; k < NN; ++k) thrmax = fmaxf(thrmax, td[k]);
        lim = fminf(thrmax, RAD2);
      }
    }
    __syncthreads();
  }

  // dump per-wave candidate lists
#pragma unroll
  for (int k = 0; k < NN; ++k) cand[(wave * 64 + lane) * 17 + k] = td[k];
  __syncthreads();

  // wave 0 merges the 4 sub-lists per point and evaluates the loss
  if (wave == 0) {
    float sd[NN];
#pragma unroll
    for (int k = 0; k < NN; ++k) sd[k] = 1e30f;
    float smax = 1e30f;
    float slim = RAD2;
    for (int w = 0; w < 4; ++w) {
      for (int c = 0; c < NN; ++c) {
        const float v = cand[(w * 64 + lane) * 17 + c];
        if (v < slim) {
          bool done = false;
#pragma unroll
          for (int k = 0; k < NN; ++k) {
            const bool hit = (!done) && (sd[k] == smax);
            if (hit) sd[k] = v;
            done = done || hit;
          }
          smax = sd[0];
#pragma unroll
          for (int k = 1; k < NN; ++k) smax = fmaxf(smax, sd[k]);
          slim = fminf(smax, RAD2);
        }
      }
    }
    float loss = 0.0f;
#pragma unroll
    for (int k = 0; k < NN; ++k) {
      if (sd[k] < RAD2) loss += 1.0f / sqrtf(sd[k] + EPSF);
    }
    // deterministic 64-lane tree reduce
    for (int off = 32; off > 0; off >>= 1) loss += __shfl_down(loss, off);
    if (lane == 0) block_sums[bid] = loss;
  }
}

__global__ __launch_bounds__(256)
void finalize_kernel(const float* __restrict__ block_sums, float* __restrict__ out) {
  __shared__ float s[256];
  float v = 0.0f;
  for (int idx = threadIdx.x; idx < NBLOCKS; idx += 256) v += block_sums[idx];
  s[threadIdx.x] = v;
  __syncthreads();
  for (int off = 128; off > 0; off >>= 1) {
    if (threadIdx.x < off) s[threadIdx.x] += s[threadIdx.x + off];
    __syncthreads();
  }
  if (threadIdx.x == 0) out[0] = s[0] / (float)(NBATCH * NPTS * NN);
}

extern "C" void kernel_launch(void* const* d_in, const int* in_sizes, int n_in,
                              void* d_out, int out_size, void* d_ws, size_t ws_size,
                              hipStream_t stream) {
  const float* pts = (const float*)d_in[0];
  float* block_sums = (float*)d_ws;   // 512 floats
  float* out = (float*)d_out;
  knn_loss_kernel<<<NBLOCKS, NTHREADS, 0, stream>>>(pts, block_sums);
  finalize_kernel<<<1, 256, 0, stream>>>(block_sums, out);
}

// Round 2
// 168.871 us; speedup vs baseline: 2.6152x; 2.6152x over previous
//
#include <hip/hip_runtime.h>

#define NPTS 8192
#define NBATCH 4
#define NN 16
#define RAD2 0.25f
#define EPSF 1e-4f
#define TILE 1024
#define PPB 64
#define NTHREADS 512
#define NWAVES 8
#define NBLOCKS (NBATCH * NPTS / PPB)   // 512
#define QCAP 13
#define QTRIG (QCAP - 3)                // safe: <=4 pushes between checks
#define BIGF 1e30f
#define CSTRIDE 17

__device__ __forceinline__ void insert16(float (&td)[NN], float& thrmax, float v) {
  // insert v into top-16-smallest list (td holds values, thrmax = max of td)
  if (v < thrmax) {
    bool done = false;
#pragma unroll
    for (int k = 0; k < NN; ++k) {
      const bool hit = (!done) && (td[k] == thrmax);
      if (hit) td[k] = v;
      done = done || hit;
    }
    thrmax = td[0];
#pragma unroll
    for (int k = 1; k < NN; ++k) thrmax = fmaxf(thrmax, td[k]);
  }
}

__device__ __forceinline__ void drain_queue(float* buf, int qbase, int& cnt,
                                            float (&td)[NN], float& thrmax) {
  for (int c = 0; c < QCAP; ++c) {
    const float v = (c < cnt) ? buf[qbase + c] : BIGF;
    insert16(td, thrmax, v);
  }
  cnt = 0;
}

__device__ __forceinline__ void push_hit(float* buf, int qbase, int& cnt, float d2) {
  // in-radius prefilter only; d2==0 exactly <=> self (min pair d2 ~5e-5 >> fp err)
  if (d2 < RAD2 && d2 != 0.0f) {
    buf[qbase + cnt] = d2;
    ++cnt;
  }
}

__device__ __forceinline__ float dist2(const float4 q, float xi, float yi, float zi) {
  const float dx = q.x - xi;
  const float dy = q.y - yi;
  const float dz = q.z - zi;
  return fmaf(dx, dx, fmaf(dy, dy, dz * dz));
}

__global__ __launch_bounds__(NTHREADS)
void knn_loss_kernel(const float* __restrict__ pts, float* __restrict__ block_sums) {
  __shared__ float4 tile[TILE];                 // 16 KiB
  __shared__ float buf[NWAVES * 64 * CSTRIDE];  // 34.8 KiB: queues (stride 13) then cand lists (stride 17)

  const int tid = threadIdx.x;
  const int wave = tid >> 6;
  const int lane = tid & 63;
  const int bid = blockIdx.x;
  const int b = bid / (NPTS / PPB);
  const int base = (bid % (NPTS / PPB)) * PPB;
  const float* __restrict__ bp = pts + (size_t)b * NPTS * 3;

  const int i = base + lane;
  const float xi = bp[i * 3 + 0];
  const float yi = bp[i * 3 + 1];
  const float zi = bp[i * 3 + 2];

  float td[NN];
#pragma unroll
  for (int k = 0; k < NN; ++k) td[k] = BIGF;
  float thrmax = BIGF;
  int cnt = 0;
  const int qbase = tid * QCAP;

  for (int tb = 0; tb < NPTS; tb += TILE) {
    for (int p = tid; p < TILE; p += NTHREADS) {
      const float* s = bp + (size_t)(tb + p) * 3;
      tile[p] = make_float4(s[0], s[1], s[2], 0.0f);
    }
    __syncthreads();
    const int jb = wave * (TILE / NWAVES);      // 128 candidates per wave per pass
    for (int jj = 0; jj < TILE / NWAVES; jj += 4) {
      const float4 q0 = tile[jb + jj + 0];      // wave-uniform addr -> broadcast
      const float4 q1 = tile[jb + jj + 1];
      const float4 q2 = tile[jb + jj + 2];
      const float4 q3 = tile[jb + jj + 3];
      const float d0 = dist2(q0, xi, yi, zi);
      const float d1 = dist2(q1, xi, yi, zi);
      const float d2v = dist2(q2, xi, yi, zi);
      const float d3 = dist2(q3, xi, yi, zi);
      push_hit(buf, qbase, cnt, d0);
      push_hit(buf, qbase, cnt, d1);
      push_hit(buf, qbase, cnt, d2v);
      push_hit(buf, qbase, cnt, d3);
      if (__any(cnt >= QTRIG)) {
        drain_queue(buf, qbase, cnt, td, thrmax);
      }
    }
    __syncthreads();
  }

  // final drain of leftovers
  drain_queue(buf, qbase, cnt, td, thrmax);
  __syncthreads();   // everyone done with queue region before cand overwrite

  // dump per-wave candidate lists (stride 17)
#pragma unroll
  for (int k = 0; k < NN; ++k) buf[tid * CSTRIDE + k] = td[k];
  __syncthreads();

  // wave 0 merges the 8 sub-lists per point and evaluates the loss
  if (wave == 0) {
    float sd[NN];
#pragma unroll
    for (int k = 0; k < NN; ++k) sd[k] = BIGF;
    float smax = BIGF;
    for (int w = 0; w < NWAVES; ++w) {
      for (int c = 0; c < NN; ++c) {
        const float v = buf[(w * 64 + lane) * CSTRIDE + c];
        insert16(sd, smax, v);   // BIGF sentinels auto-skip (not < smax)
      }
    }
    float loss = 0.0f;
#pragma unroll
    for (int k = 0; k < NN; ++k) {
      if (sd[k] < RAD2) loss += 1.0f / sqrtf(sd[k] + EPSF);
    }
    for (int off = 32; off > 0; off >>= 1) loss += __shfl_down(loss, off);
    if (lane == 0) block_sums[bid] = loss;
  }
}

__global__ __launch_bounds__(256)
void finalize_kernel(const float* __restrict__ block_sums, float* __restrict__ out) {
  __shared__ float s[256];
  float v = 0.0f;
  for (int idx = threadIdx.x; idx < NBLOCKS; idx += 256) v += block_sums[idx];
  s[threadIdx.x] = v;
  __syncthreads();
  for (int off = 128; off > 0; off >>= 1) {
    if (threadIdx.x < off) s[threadIdx.x] += s[threadIdx.x + off];
    __syncthreads();
  }
  if (threadIdx.x == 0) out[0] = s[0] / (float)(NBATCH * NPTS * NN);
}

extern "C" void kernel_launch(void* const* d_in, const int* in_sizes, int n_in,
                              void* d_out, int out_size, void* d_ws, size_t ws_size,
                              hipStream_t stream) {
  const float* pts = (const float*)d_in[0];
  float* block_sums = (float*)d_ws;   // 512 floats
  float* out = (float*)d_out;
  knn_loss_kernel<<<NBLOCKS, NTHREADS, 0, stream>>>(pts, block_sums);
  finalize_kernel<<<1, 256, 0, stream>>>(block_sums, out);
}

// Round 3
// 166.933 us; speedup vs baseline: 2.6456x; 1.0116x over previous
//
#include <hip/hip_runtime.h>

#define NPTS 8192
#define NBATCH 4
#define NTOT (NBATCH * NPTS)     // 32768
#define NN 16
#define RAD2 0.25f
#define EPSF 1e-4f
#define BIGF 1e30f

// ---- grid ----
#define GC 24                    // cells per dim, cell size 0.5, range [-6,6)
#define GC3 (GC * GC * GC)       // 13824
#define NCELLS (NBATCH * GC3)    // 55296

// ---- search kernel config ----
#define SPPB 64                  // points per block
#define SNT 512                  // 8 waves
#define SNW 8
#define SNB (NTOT / SPPB)        // 512 blocks
#define QTRIG 16
#define CSTRIDE 17

// ---- workspace layout (bytes) ----
#define WS_COUNTS 0
#define WS_CSTART (WS_COUNTS + NCELLS * 4)
#define WS_CURSOR (WS_CSTART + NCELLS * 4)
#define WS_SORTED (WS_CURSOR + NCELLS * 4)            // 16B-aligned (663552)
#define WS_BSUMS  (WS_SORTED + NTOT * 16)
#define WS_NEEDED (WS_BSUMS + SNB * 4)                // ~1.14 MB

__device__ __forceinline__ void cell3(float x, float y, float z,
                                      int& cx, int& cy, int& cz) {
  cx = min(max((int)floorf((x + 6.0f) * 2.0f), 0), GC - 1);
  cy = min(max((int)floorf((y + 6.0f) * 2.0f), 0), GC - 1);
  cz = min(max((int)floorf((z + 6.0f) * 2.0f), 0), GC - 1);
}

__device__ __forceinline__ void insert16(float (&td)[NN], float& thrmax, float v) {
  if (v < thrmax) {
    bool done = false;
#pragma unroll
    for (int k = 0; k < NN; ++k) {
      const bool hit = (!done) && (td[k] == thrmax);
      if (hit) td[k] = v;
      done = done || hit;
    }
    thrmax = td[0];
#pragma unroll
    for (int k = 1; k < NN; ++k) thrmax = fmaxf(thrmax, td[k]);
  }
}

__device__ __forceinline__ void drain_queue(float* buf, int qbase, int& cnt,
                                            float (&td)[NN], float& thrmax) {
  for (int c = 0; c < QTRIG; ++c) {
    const float v = (c < cnt) ? buf[qbase + c] : BIGF;
    insert16(td, thrmax, v);
  }
  cnt = 0;
}

__device__ __forceinline__ float dist2f4(const float4 q, float xi, float yi, float zi) {
  const float dx = q.x - xi;
  const float dy = q.y - yi;
  const float dz = q.z - zi;
  return fmaf(dx, dx, fmaf(dy, dy, dz * dz));
}

// ============ build kernels ============

__global__ __launch_bounds__(256)
void zero_kernel(int* __restrict__ counts) {
  const int i = blockIdx.x * 256 + threadIdx.x;
  if (i < NCELLS) counts[i] = 0;
}

__global__ __launch_bounds__(256)
void hist_kernel(const float* __restrict__ pts, int* __restrict__ counts) {
  const int i = blockIdx.x * 256 + threadIdx.x;
  if (i >= NTOT) return;
  const int b = i >> 13;
  const float x = pts[i * 3 + 0], y = pts[i * 3 + 1], z = pts[i * 3 + 2];
  int cx, cy, cz;
  cell3(x, y, z, cx, cy, cz);
  atomicAdd(&counts[b * GC3 + (cz * GC + cy) * GC + cx], 1);
}

__global__ __launch_bounds__(1024)
void scan_kernel(const int* __restrict__ counts, int* __restrict__ cstart,
                 int* __restrict__ cursor) {
  __shared__ int s[1024];
  const int b = blockIdx.x;
  const int tid = threadIdx.x;
  const int g0 = b * GC3;
  const int base = b * NPTS;
  int running = 0;
  for (int chunk = 0; chunk < (GC3 + 1023) / 1024; ++chunk) {
    const int idx = chunk * 1024 + tid;
    const int v = (idx < GC3) ? counts[g0 + idx] : 0;
    s[tid] = v;
    __syncthreads();
    for (int off = 1; off < 1024; off <<= 1) {
      const int t = (tid >= off) ? s[tid - off] : 0;
      __syncthreads();
      s[tid] += t;
      __syncthreads();
    }
    const int excl = s[tid] - v;
    if (idx < GC3) {
      cstart[g0 + idx] = base + running + excl;
      cursor[g0 + idx] = base + running + excl;
    }
    running += s[1023];
    __syncthreads();
  }
}

__global__ __launch_bounds__(256)
void scatter_kernel(const float* __restrict__ pts, int* __restrict__ cursor,
                    float4* __restrict__ sorted) {
  const int i = blockIdx.x * 256 + threadIdx.x;
  if (i >= NTOT) return;
  const int b = i >> 13;
  const float x = pts[i * 3 + 0], y = pts[i * 3 + 1], z = pts[i * 3 + 2];
  int cx, cy, cz;
  cell3(x, y, z, cx, cy, cz);
  const int pos = atomicAdd(&cursor[b * GC3 + (cz * GC + cy) * GC + cx], 1);
  sorted[pos] = make_float4(x, y, z, 0.0f);
}

// ============ search ============

__global__ __launch_bounds__(SNT)
void search_kernel(const float4* __restrict__ sorted, const int* __restrict__ cstart,
                   const int* __restrict__ counts, float* __restrict__ block_sums) {
  __shared__ float buf[SNT * CSTRIDE];   // per-thread queue + final cand lists

  const int tid = threadIdx.x;
  const int wave = tid >> 6;
  const int lane = tid & 63;
  const int bid = blockIdx.x;
  const int batch = bid >> 7;                      // 128 blocks per batch
  const int p = batch * NPTS + (bid & 127) * SPPB + lane;

  const float4 pt = sorted[p];
  const float xi = pt.x, yi = pt.y, zi = pt.z;
  int cx, cy, cz;
  cell3(xi, yi, zi, cx, cy, cz);

  float td[NN];
#pragma unroll
  for (int k = 0; k < NN; ++k) td[k] = BIGF;
  float thrmax = BIGF;
  int cnt = 0;
  const int qbase = tid * CSTRIDE;

  for (int m = wave; m < 27; m += SNW) {           // wave-uniform trip count
    const int nx = cx + (m % 3) - 1;
    const int ny = cy + ((m / 3) % 3) - 1;
    const int nz = cz + (m / 9) - 1;
    int s = 0, n = 0;
    if (nx >= 0 && nx < GC && ny >= 0 && ny < GC && nz >= 0 && nz < GC) {
      const int c = batch * GC3 + (nz * GC + ny) * GC + nx;
      s = cstart[c];
      n = counts[c];
    }
    for (int j = 0; j < n; ++j) {
      const float4 q = sorted[s + j];
      const float d2 = dist2f4(q, xi, yi, zi);
      // d2 == 0 exactly <=> self (min pair d2 ~5e-5 >> fp error)
      if (d2 < RAD2 && d2 != 0.0f) {
        buf[qbase + cnt] = d2;
        ++cnt;
      }
      if (__any(cnt >= QTRIG)) drain_queue(buf, qbase, cnt, td, thrmax);
    }
  }
  drain_queue(buf, qbase, cnt, td, thrmax);

  // dump per-thread top-16 into own slots (private region, no sync needed yet)
#pragma unroll
  for (int k = 0; k < NN; ++k) buf[qbase + k] = td[k];
  __syncthreads();

  // wave 0 merges the 8 sub-lists per point and evaluates the loss
  if (wave == 0) {
    float sd[NN];
#pragma unroll
    for (int k = 0; k < NN; ++k) sd[k] = BIGF;
    float smax = BIGF;
    for (int w = 0; w < SNW; ++w) {
      for (int c = 0; c < NN; ++c) {
        const float v = buf[(w * 64 + lane) * CSTRIDE + c];
        insert16(sd, smax, v);
      }
    }
    float loss = 0.0f;
#pragma unroll
    for (int k = 0; k < NN; ++k) {
      if (sd[k] < RAD2) loss += 1.0f / sqrtf(sd[k] + EPSF);
    }
    for (int off = 32; off > 0; off >>= 1) loss += __shfl_down(loss, off);
    if (lane == 0) block_sums[bid] = loss;
  }
}

__global__ __launch_bounds__(256)
void finalize_kernel(const float* __restrict__ block_sums, int nblocks,
                     float* __restrict__ out) {
  __shared__ float s[256];
  float v = 0.0f;
  for (int idx = threadIdx.x; idx < nblocks; idx += 256) v += block_sums[idx];
  s[threadIdx.x] = v;
  __syncthreads();
  for (int off = 128; off > 0; off >>= 1) {
    if (threadIdx.x < off) s[threadIdx.x] += s[threadIdx.x + off];
    __syncthreads();
  }
  if (threadIdx.x == 0) out[0] = s[0] / (float)(NBATCH * NPTS * NN);
}

// ============ dense fallback (R2 kernel, used if ws too small) ============

#define DTILE 1024
#define DNT 512
#define DNW 8
#define DNB (NTOT / 64)

__global__ __launch_bounds__(DNT)
void dense_kernel(const float* __restrict__ pts, float* __restrict__ block_sums) {
  __shared__ float4 tile[DTILE];
  __shared__ float buf[DNT * CSTRIDE];

  const int tid = threadIdx.x;
  const int wave = tid >> 6;
  const int lane = tid & 63;
  const int bid = blockIdx.x;
  const int b = bid / (NPTS / 64);
  const int base = (bid % (NPTS / 64)) * 64;
  const float* __restrict__ bp = pts + (size_t)b * NPTS * 3;

  const int i = base + lane;
  const float xi = bp[i * 3 + 0];
  const float yi = bp[i * 3 + 1];
  const float zi = bp[i * 3 + 2];

  float td[NN];
#pragma unroll
  for (int k = 0; k < NN; ++k) td[k] = BIGF;
  float thrmax = BIGF;
  int cnt = 0;
  const int qbase = tid * CSTRIDE;

  for (int tb = 0; tb < NPTS; tb += DTILE) {
    for (int p = tid; p < DTILE; p += DNT) {
      const float* s = bp + (size_t)(tb + p) * 3;
      tile[p] = make_float4(s[0], s[1], s[2], 0.0f);
    }
    __syncthreads();
    const int jb = wave * (DTILE / DNW);
    for (int jj = 0; jj < DTILE / DNW; ++jj) {
      const float d2 = dist2f4(tile[jb + jj], xi, yi, zi);
      if (d2 < RAD2 && d2 != 0.0f) {
        buf[qbase + cnt] = d2;
        ++cnt;
      }
      if (__any(cnt >= QTRIG)) drain_queue(buf, qbase, cnt, td, thrmax);
    }
    __syncthreads();
  }
  drain_queue(buf, qbase, cnt, td, thrmax);
#pragma unroll
  for (int k = 0; k < NN; ++k) buf[qbase + k] = td[k];
  __syncthreads();

  if (wave == 0) {
    float sd[NN];
#pragma unroll
    for (int k = 0; k < NN; ++k) sd[k] = BIGF;
    float smax = BIGF;
    for (int w = 0; w < DNW; ++w) {
      for (int c = 0; c < NN; ++c) {
        insert16(sd, smax, buf[(w * 64 + lane) * CSTRIDE + c]);
      }
    }
    float loss = 0.0f;
#pragma unroll
    for (int k = 0; k < NN; ++k) {
      if (sd[k] < RAD2) loss += 1.0f / sqrtf(sd[k] + EPSF);
    }
    for (int off = 32; off > 0; off >>= 1) loss += __shfl_down(loss, off);
    if (lane == 0) block_sums[bid] = loss;
  }
}

// ============ launch ============

extern "C" void kernel_launch(void* const* d_in, const int* in_sizes, int n_in,
                              void* d_out, int out_size, void* d_ws, size_t ws_size,
                              hipStream_t stream) {
  const float* pts = (const float*)d_in[0];
  float* out = (float*)d_out;
  char* ws = (char*)d_ws;

  if (ws_size >= (size_t)WS_NEEDED) {
    int* counts = (int*)(ws + WS_COUNTS);
    int* cstart = (int*)(ws + WS_CSTART);
    int* cursor = (int*)(ws + WS_CURSOR);
    float4* sorted = (float4*)(ws + WS_SORTED);
    float* bsums = (float*)(ws + WS_BSUMS);

    zero_kernel<<<(NCELLS + 255) / 256, 256, 0, stream>>>(counts);
    hist_kernel<<<(NTOT + 255) / 256, 256, 0, stream>>>(pts, counts);
    scan_kernel<<<NBATCH, 1024, 0, stream>>>(counts, cstart, cursor);
    scatter_kernel<<<(NTOT + 255) / 256, 256, 0, stream>>>(pts, cursor, sorted);
    search_kernel<<<SNB, SNT, 0, stream>>>(sorted, cstart, counts, bsums);
    finalize_kernel<<<1, 256, 0, stream>>>(bsums, SNB, out);
  } else {
    float* bsums = (float*)ws;   // DNB floats
    dense_kernel<<<DNB, DNT, 0, stream>>>(pts, bsums);
    finalize_kernel<<<1, 256, 0, stream>>>(bsums, DNB, out);
  }
}

// Round 4
// 127.133 us; speedup vs baseline: 3.4738x; 1.3131x over previous
//
#include <hip/hip_runtime.h>

#define NPTS 8192
#define NBATCH 4
#define NTOT (NBATCH * NPTS)     // 32768
#define NN 16
#define RAD2 0.25f
#define EPSF 1e-4f
#define BIGF 1e30f

// ---- grid: cell 0.5 over [-4,4), 16 real cells/dim + ghost ring -> 18^3 ----
#define GC 16
#define GP 18
#define GP3 (GP * GP * GP)       // 5832
#define CBS 6144                 // per-batch padded cell stride (6 * 1024)
#define NCELL_TOT (NBATCH * CBS) // 24576

// ---- search config: one wave per point ----
#define STHR 256                 // 4 waves
#define SWAVES 4
#define SBLK (NTOT / SWAVES)     // 8192 blocks
#define HCAP 384                 // per-wave hit cap (max expected ~340)

// ---- ws layout (bytes) ----
#define WS_COUNTS 0
#define WS_RANGES (WS_COUNTS + NCELL_TOT * 4)          // int2
#define WS_CURSOR (WS_RANGES + NCELL_TOT * 8)
#define WS_SORTED (WS_CURSOR + NCELL_TOT * 4)          // float4, 16B aligned
#define WS_BSUMS  (WS_SORTED + NTOT * 16)
#define WS_NEEDED (WS_BSUMS + SBLK * 4)                // ~0.95 MB

__device__ __forceinline__ int cellc(float v) {
  return min(max((int)floorf((v + 4.0f) * 2.0f), 0), GC - 1);
}

// ============ build ============

__global__ __launch_bounds__(256)
void zero_kernel(int* __restrict__ counts) {
  const int i = blockIdx.x * 256 + threadIdx.x;
  if (i < NCELL_TOT) counts[i] = 0;
}

__global__ __launch_bounds__(256)
void hist_kernel(const float* __restrict__ pts, int* __restrict__ counts) {
  const int i = blockIdx.x * 256 + threadIdx.x;
  if (i >= NTOT) return;
  const int b = i >> 13;
  const float x = pts[i * 3 + 0], y = pts[i * 3 + 1], z = pts[i * 3 + 2];
  const int cx = cellc(x), cy = cellc(y), cz = cellc(z);
  const int c = b * CBS + ((cz + 1) * GP + (cy + 1)) * GP + (cx + 1);
  atomicAdd(&counts[c], 1);
}

__global__ __launch_bounds__(1024)
void scan_kernel(const int* __restrict__ counts, int2* __restrict__ ranges,
                 int* __restrict__ cursor) {
  __shared__ int wsum[16];
  __shared__ int woff[16];
  __shared__ int stot;
  const int b = blockIdx.x;
  const int tid = threadIdx.x;
  const int wid = tid >> 6;
  const int lane = tid & 63;
  const int g0 = b * CBS;
  int running = b * NPTS;
  for (int chunk = 0; chunk < CBS; chunk += 1024) {
    const int idx = chunk + tid;
    const int v = counts[g0 + idx];
    int x = v;
    for (int off = 1; off < 64; off <<= 1) {
      const int t = __shfl_up(x, off, 64);
      if (lane >= off) x += t;
    }
    if (lane == 63) wsum[wid] = x;
    __syncthreads();
    if (wid == 0) {
      int s = (lane < 16) ? wsum[lane] : 0;
      for (int off = 1; off < 16; off <<= 1) {
        const int t = __shfl_up(s, off, 64);
        if (lane >= off) s += t;
      }
      if (lane < 16) woff[lane] = s - wsum[lane];
      if (lane == 15) stot = s;
    }
    __syncthreads();
    const int excl = running + woff[wid] + x - v;
    ranges[g0 + idx] = make_int2(excl, v);
    cursor[g0 + idx] = excl;
    running += stot;
    __syncthreads();
  }
}

__global__ __launch_bounds__(256)
void scatter_kernel(const float* __restrict__ pts, int* __restrict__ cursor,
                    float4* __restrict__ sorted) {
  const int i = blockIdx.x * 256 + threadIdx.x;
  if (i >= NTOT) return;
  const int b = i >> 13;
  const float x = pts[i * 3 + 0], y = pts[i * 3 + 1], z = pts[i * 3 + 2];
  const int cx = cellc(x), cy = cellc(y), cz = cellc(z);
  const int c = b * CBS + ((cz + 1) * GP + (cy + 1)) * GP + (cx + 1);
  const int pos = atomicAdd(&cursor[c], 1);
  sorted[pos] = make_float4(x, y, z, 0.0f);
}

// ============ search: one wave per point ============

#define CE(a, b) { const float lo_ = fminf(a, b); const float hi_ = fmaxf(a, b); a = lo_; b = hi_; }

__global__ __launch_bounds__(STHR)
void search_kernel(const float4* __restrict__ sorted, const int2* __restrict__ ranges,
                   float* __restrict__ bsums) {
  __shared__ float hbuf[SWAVES][HCAP];
  __shared__ float wloss[SWAVES];

  const int tid = threadIdx.x;
  const int wv = tid >> 6;
  const int lane = tid & 63;
  const int p = blockIdx.x * SWAVES + wv;
  const int b = p >> 13;

  const float4 pt = sorted[p];
  const float xi = pt.x, yi = pt.y, zi = pt.z;
  const int cx = cellc(xi), cy = cellc(yi), cz = cellc(zi);
  const int c0 = b * CBS + ((cz + 1) * GP + (cy + 1)) * GP + (cx + 1);

  float* hq = hbuf[wv];
  int hcnt = 0;

  // prefetch cell 0 range; iterate 27 neighbor cells, prefetching next
  int2 rng = ranges[c0 + ((-1) * GP + (-1)) * GP + (-1)];
  for (int m = 0; m < 27; ++m) {
    const int2 cur = rng;
    if (m < 26) {
      const int m1 = m + 1;
      const int dz = m1 / 9 - 1, dy = (m1 / 3) % 3 - 1, dx = m1 % 3 - 1;
      rng = ranges[c0 + (dz * GP + dy) * GP + dx];
    }
    const int s = cur.x, n = cur.y;
    for (int j0 = 0; j0 < n; j0 += 64) {
      const int j = j0 + lane;
      float d2 = BIGF;
      if (j < n) {
        const float4 q = sorted[s + j];
        const float ddx = q.x - xi, ddy = q.y - yi, ddz = q.z - zi;
        d2 = fmaf(ddx, ddx, fmaf(ddy, ddy, ddz * ddz));
      }
      // d2 == 0 exactly <=> self (min pair d2 ~5e-5 >> fp error)
      const bool hit = (d2 < RAD2) && (d2 != 0.0f);
      const unsigned long long bal = __ballot(hit);
      if (bal) {
        const int pre = __popcll(bal & ((1ull << lane) - 1ull));
        const int pos = hcnt + pre;
        if (hit && pos < HCAP) hq[pos] = d2;
        hcnt += (int)__popcll(bal);
      }
    }
  }

  // load up to 6 hits per lane (wave-private region; wave-ordered LDS)
  const int hn = min(hcnt, HCAP);
  float v0 = (lane < hn)       ? hq[lane]       : BIGF;
  float v1 = (lane + 64 < hn)  ? hq[lane + 64]  : BIGF;
  float v2 = (lane + 128 < hn) ? hq[lane + 128] : BIGF;
  float v3 = (lane + 192 < hn) ? hq[lane + 192] : BIGF;
  float v4 = (lane + 256 < hn) ? hq[lane + 256] : BIGF;
  float v5 = (lane + 320 < hn) ? hq[lane + 320] : BIGF;

  // per-lane sort of 6 (odd-even transposition, 6 passes)
  CE(v0, v1); CE(v2, v3); CE(v4, v5);
  CE(v1, v2); CE(v3, v4);
  CE(v0, v1); CE(v2, v3); CE(v4, v5);
  CE(v1, v2); CE(v3, v4);
  CE(v0, v1); CE(v2, v3); CE(v4, v5);
  CE(v1, v2); CE(v3, v4);

  // 16 rounds: extract global min, accumulate loss (ascending order -> deterministic)
  float loss = 0.0f;
  for (int r = 0; r < NN; ++r) {
    float gmin = v0;
    gmin = fminf(gmin, __shfl_xor(gmin, 1, 64));
    gmin = fminf(gmin, __shfl_xor(gmin, 2, 64));
    gmin = fminf(gmin, __shfl_xor(gmin, 4, 64));
    gmin = fminf(gmin, __shfl_xor(gmin, 8, 64));
    gmin = fminf(gmin, __shfl_xor(gmin, 16, 64));
    gmin = fminf(gmin, __shfl_xor(gmin, 32, 64));
    if (gmin >= RAD2) break;               // uniform across wave
    loss += 1.0f / sqrtf(gmin + EPSF);
    const unsigned long long own = __ballot(v0 == gmin);
    const int first = (int)(__ffsll((long long)own) - 1);
    if (lane == first) { v0 = v1; v1 = v2; v2 = v3; v3 = v4; v4 = v5; v5 = BIGF; }
  }

  if (lane == 0) wloss[wv] = loss;
  __syncthreads();
  if (tid == 0) bsums[blockIdx.x] = wloss[0] + wloss[1] + wloss[2] + wloss[3];
}

__global__ __launch_bounds__(256)
void finalize_kernel(const float* __restrict__ block_sums, int nblocks,
                     float* __restrict__ out) {
  __shared__ float s[256];
  float v = 0.0f;
  for (int idx = threadIdx.x; idx < nblocks; idx += 256) v += block_sums[idx];
  s[threadIdx.x] = v;
  __syncthreads();
  for (int off = 128; off > 0; off >>= 1) {
    if (threadIdx.x < off) s[threadIdx.x] += s[threadIdx.x + off];
    __syncthreads();
  }
  if (threadIdx.x == 0) out[0] = s[0] / (float)(NBATCH * NPTS * NN);
}

// ============ dense fallback (if ws too small) ============

#define DTILE 1024
#define DNT 512
#define DNW 8
#define DNB (NTOT / 64)
#define CSTRIDE 17
#define QTRIG 16

__device__ __forceinline__ void insert16(float (&td)[NN], float& thrmax, float v) {
  if (v < thrmax) {
    bool done = false;
#pragma unroll
    for (int k = 0; k < NN; ++k) {
      const bool hit = (!done) && (td[k] == thrmax);
      if (hit) td[k] = v;
      done = done || hit;
    }
    thrmax = td[0];
#pragma unroll
    for (int k = 1; k < NN; ++k) thrmax = fmaxf(thrmax, td[k]);
  }
}

__device__ __forceinline__ void drain_queue(float* buf, int qbase, int& cnt,
                                            float (&td)[NN], float& thrmax) {
  for (int c = 0; c < QTRIG; ++c) {
    const float v = (c < cnt) ? buf[qbase + c] : BIGF;
    insert16(td, thrmax, v);
  }
  cnt = 0;
}

__global__ __launch_bounds__(DNT)
void dense_kernel(const float* __restrict__ pts, float* __restrict__ block_sums) {
  __shared__ float4 tile[DTILE];
  __shared__ float buf[DNT * CSTRIDE];

  const int tid = threadIdx.x;
  const int wave = tid >> 6;
  const int lane = tid & 63;
  const int bid = blockIdx.x;
  const int b = bid / (NPTS / 64);
  const int base = (bid % (NPTS / 64)) * 64;
  const float* __restrict__ bp = pts + (size_t)b * NPTS * 3;

  const int i = base + lane;
  const float xi = bp[i * 3 + 0];
  const float yi = bp[i * 3 + 1];
  const float zi = bp[i * 3 + 2];

  float td[NN];
#pragma unroll
  for (int k = 0; k < NN; ++k) td[k] = BIGF;
  float thrmax = BIGF;
  int cnt = 0;
  const int qbase = tid * CSTRIDE;

  for (int tb = 0; tb < NPTS; tb += DTILE) {
    for (int pp = tid; pp < DTILE; pp += DNT) {
      const float* sp = bp + (size_t)(tb + pp) * 3;
      tile[pp] = make_float4(sp[0], sp[1], sp[2], 0.0f);
    }
    __syncthreads();
    const int jb = wave * (DTILE / DNW);
    for (int jj = 0; jj < DTILE / DNW; ++jj) {
      const float4 q = tile[jb + jj];
      const float ddx = q.x - xi, ddy = q.y - yi, ddz = q.z - zi;
      const float d2 = fmaf(ddx, ddx, fmaf(ddy, ddy, ddz * ddz));
      if (d2 < RAD2 && d2 != 0.0f) {
        buf[qbase + cnt] = d2;
        ++cnt;
      }
      if (__any(cnt >= QTRIG)) drain_queue(buf, qbase, cnt, td, thrmax);
    }
    __syncthreads();
  }
  drain_queue(buf, qbase, cnt, td, thrmax);
#pragma unroll
  for (int k = 0; k < NN; ++k) buf[qbase + k] = td[k];
  __syncthreads();

  if (wave == 0) {
    float sd[NN];
#pragma unroll
    for (int k = 0; k < NN; ++k) sd[k] = BIGF;
    float smax = BIGF;
    for (int w = 0; w < DNW; ++w) {
      for (int c = 0; c < NN; ++c) {
        insert16(sd, smax, buf[(w * 64 + lane) * CSTRIDE + c]);
      }
    }
    float loss = 0.0f;
#pragma unroll
    for (int k = 0; k < NN; ++k) {
      if (sd[k] < RAD2) loss += 1.0f / sqrtf(sd[k] + EPSF);
    }
    for (int off = 32; off > 0; off >>= 1) loss += __shfl_down(loss, off);
    if (lane == 0) block_sums[bid] = loss;
  }
}

// ============ launch ============

extern "C" void kernel_launch(void* const* d_in, const int* in_sizes, int n_in,
                              void* d_out, int out_size, void* d_ws, size_t ws_size,
                              hipStream_t stream) {
  const float* pts = (const float*)d_in[0];
  float* out = (float*)d_out;
  char* ws = (char*)d_ws;

  if (ws_size >= (size_t)WS_NEEDED) {
    int* counts = (int*)(ws + WS_COUNTS);
    int2* rngs = (int2*)(ws + WS_RANGES);
    int* cursor = (int*)(ws + WS_CURSOR);
    float4* sorted = (float4*)(ws + WS_SORTED);
    float* bsums = (float*)(ws + WS_BSUMS);

    zero_kernel<<<(NCELL_TOT + 255) / 256, 256, 0, stream>>>(counts);
    hist_kernel<<<(NTOT + 255) / 256, 256, 0, stream>>>(pts, counts);
    scan_kernel<<<NBATCH, 1024, 0, stream>>>(counts, rngs, cursor);
    scatter_kernel<<<(NTOT + 255) / 256, 256, 0, stream>>>(pts, cursor, sorted);
    search_kernel<<<SBLK, STHR, 0, stream>>>(sorted, rngs, bsums);
    finalize_kernel<<<1, 256, 0, stream>>>(bsums, SBLK, out);
  } else {
    float* bsums = (float*)ws;
    dense_kernel<<<DNB, DNT, 0, stream>>>(pts, bsums);
    finalize_kernel<<<1, 256, 0, stream>>>(bsums, DNB, out);
  }
}

// Round 5
// 80.201 us; speedup vs baseline: 5.5066x; 1.5852x over previous
//
#include <hip/hip_runtime.h>

#define NPTS 8192
#define NBATCH 4
#define NTOT (NBATCH * NPTS)     // 32768
#define NN 16
#define RAD2 0.25f
#define EPSF 1e-4f
#define BIGF 1e30f

// ---- grid: cell 0.5 over [-4,4), 16 real cells/dim + ghost ring -> 18^3 ----
#define GC 16
#define GP 18
#define CBS 6144                 // per-batch padded cell stride (6 * 1024 >= 18^3)
#define NCELL_TOT (NBATCH * CBS) // 24576

// ---- search config: one wave per point ----
#define STHR 256                 // 4 waves
#define SWAVES 4
#define SBLK (NTOT / SWAVES)     // 8192 blocks
#define HCAP 192                 // per-point in-radius hits: mean ~12, max ~70 -> big margin

// ---- ws layout (bytes) ----
#define WS_COUNTS 0
#define WS_RANGES (WS_COUNTS + NCELL_TOT * 4)          // int2
#define WS_CURSOR (WS_RANGES + NCELL_TOT * 8)
#define WS_SORTED (WS_CURSOR + NCELL_TOT * 4)          // float4, 16B aligned
#define WS_BSUMS  (WS_SORTED + NTOT * 16)
#define WS_NEEDED (WS_BSUMS + SBLK * 4)

__device__ __forceinline__ int cellc(float v) {
  return min(max((int)floorf((v + 4.0f) * 2.0f), 0), GC - 1);
}

// refined rsqrt: v_rsq + one Newton step (~1-2 ulp; mean over 512K terms absorbs it)
__device__ __forceinline__ float prsqrt(float x) {
  float r = __builtin_amdgcn_rsqf(x);
  r = r * fmaf(-0.5f * x * r, r, 1.5f);
  return r;
}

__device__ __forceinline__ int lane_prefix(unsigned long long m) {
  return __builtin_amdgcn_mbcnt_hi((unsigned)(m >> 32),
         __builtin_amdgcn_mbcnt_lo((unsigned)m, 0));
}

// ============ build ============

__global__ __launch_bounds__(256)
void zero_kernel(int* __restrict__ counts) {
  const int i = blockIdx.x * 256 + threadIdx.x;
  if (i < NCELL_TOT) counts[i] = 0;
}

__global__ __launch_bounds__(256)
void hist_kernel(const float* __restrict__ pts, int* __restrict__ counts) {
  const int i = blockIdx.x * 256 + threadIdx.x;
  if (i >= NTOT) return;
  const int b = i >> 13;
  const float x = pts[i * 3 + 0], y = pts[i * 3 + 1], z = pts[i * 3 + 2];
  const int cx = cellc(x), cy = cellc(y), cz = cellc(z);
  const int c = b * CBS + ((cz + 1) * GP + (cy + 1)) * GP + (cx + 1);
  atomicAdd(&counts[c], 1);
}

__global__ __launch_bounds__(1024)
void scan_kernel(const int* __restrict__ counts, int2* __restrict__ ranges,
                 int* __restrict__ cursor) {
  __shared__ int wsum[16];
  __shared__ int woff[16];
  __shared__ int stot;
  const int b = blockIdx.x;
  const int tid = threadIdx.x;
  const int wid = tid >> 6;
  const int lane = tid & 63;
  const int g0 = b * CBS;
  int running = b * NPTS;
  for (int chunk = 0; chunk < CBS; chunk += 1024) {
    const int idx = chunk + tid;
    const int v = counts[g0 + idx];
    int x = v;
    for (int off = 1; off < 64; off <<= 1) {
      const int t = __shfl_up(x, off, 64);
      if (lane >= off) x += t;
    }
    if (lane == 63) wsum[wid] = x;
    __syncthreads();
    if (wid == 0) {
      int s = (lane < 16) ? wsum[lane] : 0;
      for (int off = 1; off < 16; off <<= 1) {
        const int t = __shfl_up(s, off, 64);
        if (lane >= off) s += t;
      }
      if (lane < 16) woff[lane] = s - wsum[lane];
      if (lane == 15) stot = s;
    }
    __syncthreads();
    const int excl = running + woff[wid] + x - v;
    ranges[g0 + idx] = make_int2(excl, v);
    cursor[g0 + idx] = excl;
    running += stot;
    __syncthreads();
  }
}

__global__ __launch_bounds__(256)
void scatter_kernel(const float* __restrict__ pts, int* __restrict__ cursor,
                    float4* __restrict__ sorted) {
  const int i = blockIdx.x * 256 + threadIdx.x;
  if (i >= NTOT) return;
  const int b = i >> 13;
  const float x = pts[i * 3 + 0], y = pts[i * 3 + 1], z = pts[i * 3 + 2];
  const int cx = cellc(x), cy = cellc(y), cz = cellc(z);
  const int c = b * CBS + ((cz + 1) * GP + (cy + 1)) * GP + (cx + 1);
  const int pos = atomicAdd(&cursor[c], 1);
  sorted[pos] = make_float4(x, y, z, 0.0f);
}

// ============ search: one wave per point, 9 merged x-rows ============

#define CE(a, b) { const float lo_ = fminf(a, b); const float hi_ = fmaxf(a, b); a = lo_; b = hi_; }

__global__ __launch_bounds__(STHR)
void search_kernel(const float4* __restrict__ sorted, const int2* __restrict__ rngs,
                   float* __restrict__ bsums) {
  __shared__ float hbuf[SWAVES][HCAP];
  __shared__ float wloss[SWAVES];

  const int tid = threadIdx.x;
  const int wv = tid >> 6;
  const int lane = tid & 63;
  const int p = blockIdx.x * SWAVES + wv;
  const int b = p >> 13;

  const float4 pt = sorted[p];
  const float xi = pt.x, yi = pt.y, zi = pt.z;
  const int cx = cellc(xi), cy = cellc(yi), cz = cellc(zi);
  // wave-uniform by construction; readfirstlane pins it to SGPR -> s_load ranges
  const int c0 = __builtin_amdgcn_readfirstlane(
      b * CBS + ((cz + 1) * GP + (cy + 1)) * GP + (cx + 1));

  float* hq = hbuf[wv];
  int hcnt = 0;

  // 9 rows: 3 contiguous x-cells merged into one range each (x-fastest layout)
  const int rowoff[9] = {
    (-1 * GP - 1) * GP, (-1 * GP + 0) * GP, (-1 * GP + 1) * GP,
    ( 0 * GP - 1) * GP, ( 0 * GP + 0) * GP, ( 0 * GP + 1) * GP,
    ( 1 * GP - 1) * GP, ( 1 * GP + 0) * GP, ( 1 * GP + 1) * GP };
#pragma unroll
  for (int m = 0; m < 9; ++m) {
    const int2 a = rngs[c0 + rowoff[m] - 1];   // dx=-1 cell
    const int2 e = rngs[c0 + rowoff[m] + 1];   // dx=+1 cell
    const int s = a.x;
    const int n = (e.x + e.y) - a.x;           // merged row length
    for (int j0 = 0; j0 < n; j0 += 64) {
      const int j = j0 + lane;
      float d2 = BIGF;
      if (j < n) {
        const float4 q = sorted[s + j];
        const float ddx = q.x - xi, ddy = q.y - yi, ddz = q.z - zi;
        d2 = fmaf(ddx, ddx, fmaf(ddy, ddy, ddz * ddz));
      }
      // d2 == 0 exactly <=> self (min pair d2 ~5e-5 >> fp error)
      const bool hit = (d2 < RAD2) && (d2 != 0.0f);
      const unsigned long long bal = __ballot(hit);
      if (bal) {
        const int pos = hcnt + lane_prefix(bal);
        if (hit && pos < HCAP) hq[pos] = d2;
        hcnt += (int)__popcll(bal);
      }
    }
  }

  const int hn = min(hcnt, HCAP);
  float loss;
  if (hn <= NN) {
    // all hits contribute; no selection needed
    const float v = (lane < hn) ? hq[lane] : BIGF;
    float l = (v < RAD2) ? prsqrt(v + EPSF) : 0.0f;
    l += __shfl_xor(l, 1);
    l += __shfl_xor(l, 2);
    l += __shfl_xor(l, 4);
    l += __shfl_xor(l, 8);
    l += __shfl_xor(l, 16);
    l += __shfl_xor(l, 32);
    loss = l;
  } else {
    // tournament over per-lane sorted triples (hn <= 192)
    float v0 = (lane < hn)       ? hq[lane]       : BIGF;
    float v1 = (lane + 64 < hn)  ? hq[lane + 64]  : BIGF;
    float v2 = (lane + 128 < hn) ? hq[lane + 128] : BIGF;
    CE(v0, v1); CE(v1, v2); CE(v0, v1);   // sort3 ascending
    loss = 0.0f;
#pragma unroll
    for (int r = 0; r < NN; ++r) {
      float g = v0;
      g = fminf(g, __shfl_xor(g, 1));
      g = fminf(g, __shfl_xor(g, 2));
      g = fminf(g, __shfl_xor(g, 4));
      g = fminf(g, __shfl_xor(g, 8));
      g = fminf(g, __shfl_xor(g, 16));
      g = fminf(g, __shfl_xor(g, 32));
      loss += prsqrt(g + EPSF);           // hn > 16 => 16 valid mins, all < RAD2
      const unsigned long long own = __ballot(v0 == g);
      const int first = (int)(__ffsll((unsigned long long)own) - 1);
      if (lane == first) { v0 = v1; v1 = v2; v2 = BIGF; }
    }
  }

  if (lane == 0) wloss[wv] = loss;
  __syncthreads();
  if (tid == 0) bsums[blockIdx.x] = wloss[0] + wloss[1] + wloss[2] + wloss[3];
}

__global__ __launch_bounds__(256)
void finalize_kernel(const float* __restrict__ block_sums, int nblocks,
                     float* __restrict__ out) {
  __shared__ float s[256];
  float v = 0.0f;
  for (int idx = threadIdx.x; idx < nblocks; idx += 256) v += block_sums[idx];
  s[threadIdx.x] = v;
  __syncthreads();
  for (int off = 128; off > 0; off >>= 1) {
    if (threadIdx.x < off) s[threadIdx.x] += s[threadIdx.x + off];
    __syncthreads();
  }
  if (threadIdx.x == 0) out[0] = s[0] / (float)(NBATCH * NPTS * NN);
}

// ============ dense fallback (if ws too small) ============

#define DTILE 1024
#define DNT 512
#define DNW 8
#define DNB (NTOT / 64)
#define CSTRIDE 17
#define QTRIG 16

__device__ __forceinline__ void insert16(float (&td)[NN], float& thrmax, float v) {
  if (v < thrmax) {
    bool done = false;
#pragma unroll
    for (int k = 0; k < NN; ++k) {
      const bool hit = (!done) && (td[k] == thrmax);
      if (hit) td[k] = v;
      done = done || hit;
    }
    thrmax = td[0];
#pragma unroll
    for (int k = 1; k < NN; ++k) thrmax = fmaxf(thrmax, td[k]);
  }
}

__device__ __forceinline__ void drain_queue(float* buf, int qbase, int& cnt,
                                            float (&td)[NN], float& thrmax) {
  for (int c = 0; c < QTRIG; ++c) {
    const float v = (c < cnt) ? buf[qbase + c] : BIGF;
    insert16(td, thrmax, v);
  }
  cnt = 0;
}

__global__ __launch_bounds__(DNT)
void dense_kernel(const float* __restrict__ pts, float* __restrict__ block_sums) {
  __shared__ float4 tile[DTILE];
  __shared__ float buf[DNT * CSTRIDE];

  const int tid = threadIdx.x;
  const int wave = tid >> 6;
  const int lane = tid & 63;
  const int bid = blockIdx.x;
  const int b = bid / (NPTS / 64);
  const int base = (bid % (NPTS / 64)) * 64;
  const float* __restrict__ bp = pts + (size_t)b * NPTS * 3;

  const int i = base + lane;
  const float xi = bp[i * 3 + 0];
  const float yi = bp[i * 3 + 1];
  const float zi = bp[i * 3 + 2];

  float td[NN];
#pragma unroll
  for (int k = 0; k < NN; ++k) td[k] = BIGF;
  float thrmax = BIGF;
  int cnt = 0;
  const int qbase = tid * CSTRIDE;

  for (int tb = 0; tb < NPTS; tb += DTILE) {
    for (int pp = tid; pp < DTILE; pp += DNT) {
      const float* sp = bp + (size_t)(tb + pp) * 3;
      tile[pp] = make_float4(sp[0], sp[1], sp[2], 0.0f);
    }
    __syncthreads();
    const int jb = wave * (DTILE / DNW);
    for (int jj = 0; jj < DTILE / DNW; ++jj) {
      const float4 q = tile[jb + jj];
      const float ddx = q.x - xi, ddy = q.y - yi, ddz = q.z - zi;
      const float d2 = fmaf(ddx, ddx, fmaf(ddy, ddy, ddz * ddz));
      if (d2 < RAD2 && d2 != 0.0f) {
        buf[qbase + cnt] = d2;
        ++cnt;
      }
      if (__any(cnt >= QTRIG)) drain_queue(buf, qbase, cnt, td, thrmax);
    }
    __syncthreads();
  }
  drain_queue(buf, qbase, cnt, td, thrmax);
#pragma unroll
  for (int k = 0; k < NN; ++k) buf[qbase + k] = td[k];
  __syncthreads();

  if (wave == 0) {
    float sd[NN];
#pragma unroll
    for (int k = 0; k < NN; ++k) sd[k] = BIGF;
    float smax = BIGF;
    for (int w = 0; w < DNW; ++w) {
      for (int c = 0; c < NN; ++c) {
        insert16(sd, smax, buf[(w * 64 + lane) * CSTRIDE + c]);
      }
    }
    float loss = 0.0f;
#pragma unroll
    for (int k = 0; k < NN; ++k) {
      if (sd[k] < RAD2) loss += 1.0f / sqrtf(sd[k] + EPSF);
    }
    for (int off = 32; off > 0; off >>= 1) loss += __shfl_down(loss, off);
    if (lane == 0) block_sums[bid] = loss;
  }
}

// ============ launch ============

extern "C" void kernel_launch(void* const* d_in, const int* in_sizes, int n_in,
                              void* d_out, int out_size, void* d_ws, size_t ws_size,
                              hipStream_t stream) {
  const float* pts = (const float*)d_in[0];
  float* out = (float*)d_out;
  char* ws = (char*)d_ws;

  if (ws_size >= (size_t)WS_NEEDED) {
    int* counts = (int*)(ws + WS_COUNTS);
    int2* rngs = (int2*)(ws + WS_RANGES);
    int* cursor = (int*)(ws + WS_CURSOR);
    float4* sorted = (float4*)(ws + WS_SORTED);
    float* bsums = (float*)(ws + WS_BSUMS);

    zero_kernel<<<(NCELL_TOT + 255) / 256, 256, 0, stream>>>(counts);
    hist_kernel<<<(NTOT + 255) / 256, 256, 0, stream>>>(pts, counts);
    scan_kernel<<<NBATCH, 1024, 0, stream>>>(counts, rngs, cursor);
    scatter_kernel<<<(NTOT + 255) / 256, 256, 0, stream>>>(pts, cursor, sorted);
    search_kernel<<<SBLK, STHR, 0, stream>>>(sorted, rngs, bsums);
    finalize_kernel<<<1, 256, 0, stream>>>(bsums, SBLK, out);
  } else {
    float* bsums = (float*)ws;
    dense_kernel<<<DNB, DNT, 0, stream>>>(pts, bsums);
    finalize_kernel<<<1, 256, 0, stream>>>(bsums, DNB, out);
  }
}